// Round 1
// baseline (30.026 us; speedup 1.0000x reference)
//
#include <hip/hip_runtime.h>

// Problem constants from the reference: x,y are [B=8, T=2048, C=1024] fp32.
// -mean(einsum('itj,itl->ijl', x, y)) ==
// -(1/(B*C*C)) * sum_{i,t} rowsum(x[i,t,:]) * rowsum(y[i,t,:])
#define N_ROWS (8 * 2048)   // B*T
#define N_C    1024
#define DENOM  (8.0 * 1024.0 * 1024.0)  // B*C*C

#define BLOCKS 1024
#define THREADS 256
#define N_WAVES (BLOCKS * (THREADS / 64))  // 4096 partials

__global__ __launch_bounds__(THREADS)
void corr_rowsum_partial(const float* __restrict__ x,
                         const float* __restrict__ y,
                         double* __restrict__ partials) {
    const int lane = threadIdx.x & 63;
    const int waveInBlock = threadIdx.x >> 6;
    const int wave = blockIdx.x * (THREADS / 64) + waveInBlock;

    double acc = 0.0;
    // Each wave owns rows wave, wave+N_WAVES, ... (grid-stride over rows).
    for (int row = wave; row < N_ROWS; row += N_WAVES) {
        const float4* xr = (const float4*)(x + (size_t)row * N_C);
        const float4* yr = (const float4*)(y + (size_t)row * N_C);
        float sx = 0.f, sy = 0.f;
        // 1024 floats per row = 256 float4; 64 lanes * 4 float4 each, coalesced.
        #pragma unroll
        for (int k = 0; k < 4; ++k) {
            float4 vx = xr[lane + 64 * k];
            float4 vy = yr[lane + 64 * k];
            sx += (vx.x + vx.y) + (vx.z + vx.w);
            sy += (vy.x + vy.y) + (vy.z + vy.w);
        }
        // Wave-wide butterfly reduction (64 lanes).
        #pragma unroll
        for (int off = 32; off > 0; off >>= 1) {
            sx += __shfl_xor(sx, off, 64);
            sy += __shfl_xor(sy, off, 64);
        }
        acc += (double)sx * (double)sy;  // same value in all lanes
    }
    if (lane == 0) partials[wave] = acc;
}

__global__ __launch_bounds__(256)
void corr_final_reduce(const double* __restrict__ partials,
                       float* __restrict__ out) {
    __shared__ double sdata[256];
    double acc = 0.0;
    for (int i = threadIdx.x; i < N_WAVES; i += 256) acc += partials[i];
    sdata[threadIdx.x] = acc;
    __syncthreads();
    for (int s = 128; s > 0; s >>= 1) {
        if (threadIdx.x < s) sdata[threadIdx.x] += sdata[threadIdx.x + s];
        __syncthreads();
    }
    if (threadIdx.x == 0) out[0] = (float)(-sdata[0] / DENOM);
}

extern "C" void kernel_launch(void* const* d_in, const int* in_sizes, int n_in,
                              void* d_out, int out_size, void* d_ws, size_t ws_size,
                              hipStream_t stream) {
    const float* x = (const float*)d_in[0];
    const float* y = (const float*)d_in[1];
    float* out = (float*)d_out;
    double* partials = (double*)d_ws;  // needs N_WAVES * 8 = 32 KiB

    corr_rowsum_partial<<<BLOCKS, THREADS, 0, stream>>>(x, y, partials);
    corr_final_reduce<<<1, 256, 0, stream>>>(partials, out);
}